// Round 1
// baseline (28.483 us; speedup 1.0000x reference)
//
#include <hip/hip_runtime.h>

#define LOOKBACK 8
#define HID 32
#define MV 11
#define TB 256
#define NPOS (TB + LOOKBACK)
#define KSTRIDE (HID + 1)   // 33-float row stride: conflict-free for consecutive-row reads
#define EPS 1e-6f

__device__ __forceinline__ void ga_embed_pt(const float4 xv, float sb,
                                            const float* vs, const float* vb,
                                            const float* bw, float* m) {
    m[0]  = 1.0f + sb;
    m[1]  = xv.x * vs[0] + vb[0];
    m[2]  = xv.y * vs[1] + vb[1];
    m[3]  = xv.z * vs[2] + vb[2];
    m[4]  = xv.w * vs[3] + vb[3];
    m[5]  = bw[0] * (xv.x - xv.y);
    m[6]  = bw[1] * (xv.x - xv.z);
    m[7]  = bw[2] * (xv.x - xv.w);
    m[8]  = bw[3] * (xv.y - xv.z);
    m[9]  = bw[4] * (xv.y - xv.w);
    m[10] = bw[5] * (xv.z - xv.w);
}

__global__ __launch_bounds__(TB) void ga_attn_kernel(
    const float* __restrict__ x,            // (B, L, 4)
    const float* __restrict__ scalar_bias,  // (1,)
    const float* __restrict__ vector_scale, // (4,)
    const float* __restrict__ vector_bias,  // (4,)
    const float* __restrict__ bivector_weight, // (6,)
    const float* __restrict__ W_Q,          // (11, 32) row-major
    const float* __restrict__ W_K,
    const float* __restrict__ W_V,
    const float* __restrict__ w_head,       // (32,)
    const float* __restrict__ b_head,       // scalar
    float* __restrict__ out,                // pred (B*T) then weights (B*T*8)
    int B, int L)
{
    const int T   = L - LOOKBACK;
    const int bb  = blockIdx.y;
    const int t0  = blockIdx.x * TB;
    const int tid = threadIdx.x;

    __shared__ float sWQ[MV * HID];
    __shared__ float sWK[MV * HID];
    __shared__ float sWV[MV * HID];
    __shared__ float sK[NPOS * KSTRIDE];
    __shared__ float sVW[NPOS];

    for (int i = tid; i < MV * HID; i += TB) {
        sWQ[i] = W_Q[i];
        sWK[i] = W_K[i];
        sWV[i] = W_V[i];
    }

    // Uniform scalar params (compiler emits s_loads; cached)
    const float sb = scalar_bias[0];
    float vs[4], vb[4], bw[6];
#pragma unroll
    for (int i = 0; i < 4; ++i) { vs[i] = vector_scale[i]; vb[i] = vector_bias[i]; }
#pragma unroll
    for (int i = 0; i < 6; ++i) bw[i] = bivector_weight[i];
    const float bh = b_head[0];

    __syncthreads();

    // ---- Phase A: K (phi-activated) and V.w_head for positions [t0, t0+npos) ----
    const int npos = min(NPOS, L - t0);
    for (int pos = tid; pos < npos; pos += TB) {
        const int gl = t0 + pos;
        const float4 xv = *reinterpret_cast<const float4*>(x + ((size_t)bb * L + gl) * 4);
        float m[MV];
        ga_embed_pt(xv, sb, vs, vb, bw, m);
        float vw = 0.0f;
#pragma unroll
        for (int h = 0; h < HID; ++h) {
            float kk = 0.0f, vv = 0.0f;
#pragma unroll
            for (int j = 0; j < MV; ++j) {
                kk += m[j] * sWK[j * HID + h];
                vv += m[j] * sWV[j * HID + h];
            }
            kk = (kk >= 0.0f ? kk : 0.01f * kk) + 1.0f;  // phi
            sK[pos * KSTRIDE + h] = kk;
            vw += vv * w_head[h];
        }
        sVW[pos] = vw;
    }
    __syncthreads();

    // ---- Phase B: per-thread q, 8 window dots, outputs ----
    const int t = t0 + tid;
    if (t < T) {
        const int glq = t + LOOKBACK;
        const float4 xv = *reinterpret_cast<const float4*>(x + ((size_t)bb * L + glq) * 4);
        float m[MV];
        ga_embed_pt(xv, sb, vs, vb, bw, m);
        float q[HID];
#pragma unroll
        for (int h = 0; h < HID; ++h) {
            float qq = 0.0f;
#pragma unroll
            for (int j = 0; j < MV; ++j) qq += m[j] * sWQ[j * HID + h];
            q[h] = (qq >= 0.0f ? qq : 0.01f * qq) + 1.0f;  // phi
        }

        float sc[LOOKBACK];
        float ssum = 0.0f, p = 0.0f;
#pragma unroll
        for (int l = 0; l < LOOKBACK; ++l) {
            const int row = tid + l;
            const float* kr = &sK[row * KSTRIDE];
            float s = 0.0f;
#pragma unroll
            for (int h = 0; h < HID; ++h) s += q[h] * kr[h];
            sc[l] = s;
            ssum += s;
            p += s * sVW[row];
        }
        const float inv = 1.0f / (ssum + EPS);

        out[(size_t)bb * T + t] = p * inv + bh;

        float* wout = out + (size_t)B * T + ((size_t)bb * T + t) * LOOKBACK;
        float4 w0 = make_float4(sc[0] * inv, sc[1] * inv, sc[2] * inv, sc[3] * inv);
        float4 w1 = make_float4(sc[4] * inv, sc[5] * inv, sc[6] * inv, sc[7] * inv);
        *reinterpret_cast<float4*>(wout)     = w0;
        *reinterpret_cast<float4*>(wout + 4) = w1;
    }
}

extern "C" void kernel_launch(void* const* d_in, const int* in_sizes, int n_in,
                              void* d_out, int out_size, void* d_ws, size_t ws_size,
                              hipStream_t stream) {
    const float* x  = (const float*)d_in[0];
    const float* sb = (const float*)d_in[1];
    const float* vs = (const float*)d_in[2];
    const float* vb = (const float*)d_in[3];
    const float* bw = (const float*)d_in[4];
    const float* WQ = (const float*)d_in[5];
    const float* WK = (const float*)d_in[6];
    const float* WV = (const float*)d_in[7];
    const float* wh = (const float*)d_in[8];
    const float* bh = (const float*)d_in[9];
    float* out = (float*)d_out;

    // in_sizes[0] = B*L*4 ; out_size = B*(L-LOOKBACK)*(1+LOOKBACK)
    const long long bl = (long long)in_sizes[0] / 4;            // B*L
    const long long bt = (long long)out_size / (1 + LOOKBACK);  // B*(L-8)
    const int B = (int)((bl - bt) / LOOKBACK);
    const int L = (int)(bl / B);
    const int T = L - LOOKBACK;

    dim3 grid((T + TB - 1) / TB, B);
    ga_attn_kernel<<<grid, TB, 0, stream>>>(x, sb, vs, vb, bw, WQ, WK, WV, wh, bh,
                                            out, B, L);
}

// Round 2
// 18.338 us; speedup vs baseline: 1.5532x; 1.5532x over previous
//
#include <hip/hip_runtime.h>

#define LOOKBACK 8
#define HID 32
#define TB 256
#define NPOS (TB + LOOKBACK)
#define KST 36          // floats; 144B row stride: 16B-aligned, near-conflict-free b128
#define EPS 1e-6f

// d_ws float layout (written by prep_kernel every call)
#define WS_AQ  0     // [4][32]  A_Q
#define WS_CQ  128   // [32]     c_Q
#define WS_AK  160   // [4][32]  A_K
#define WS_CK  288   // [32]     c_K
#define WS_AVW 320   // [4]      a_vw
#define WS_CVW 324   // scalar   c_vw

__global__ __launch_bounds__(64) void prep_kernel(
    const float* __restrict__ sb, const float* __restrict__ vs,
    const float* __restrict__ vb, const float* __restrict__ bw,
    const float* __restrict__ WQ, const float* __restrict__ WK,
    const float* __restrict__ WV, const float* __restrict__ wh,
    float* __restrict__ P)
{
    const int h = threadIdx.x;
    if (h >= HID) return;

    float wq[11], wk[11], wv[11];
#pragma unroll
    for (int j = 0; j < 11; ++j) {
        wq[j] = WQ[j * HID + h];
        wk[j] = WK[j * HID + h];
        wv[j] = WV[j * HID + h];
    }
    float b0 = bw[0], b1 = bw[1], b2 = bw[2], b3 = bw[3], b4 = bw[4], b5 = bw[5];
    float v0 = vs[0], v1 = vs[1], v2 = vs[2], v3 = vs[3];
    float u0 = vb[0], u1 = vb[1], u2 = vb[2], u3 = vb[3];
    float s0 = 1.0f + sb[0];

    // A[d][h]: x_d coefficient.  BIV_I=[0,0,0,1,1,2], BIV_J=[1,2,3,2,3,3]
    float aq[4], ak[4], av[4];
    aq[0] = v0*wq[1] + b0*wq[5] + b1*wq[6] + b2*wq[7];
    aq[1] = v1*wq[2] - b0*wq[5] + b3*wq[8] + b4*wq[9];
    aq[2] = v2*wq[3] - b1*wq[6] - b3*wq[8] + b5*wq[10];
    aq[3] = v3*wq[4] - b2*wq[7] - b4*wq[9] - b5*wq[10];
    ak[0] = v0*wk[1] + b0*wk[5] + b1*wk[6] + b2*wk[7];
    ak[1] = v1*wk[2] - b0*wk[5] + b3*wk[8] + b4*wk[9];
    ak[2] = v2*wk[3] - b1*wk[6] - b3*wk[8] + b5*wk[10];
    ak[3] = v3*wk[4] - b2*wk[7] - b4*wk[9] - b5*wk[10];
    av[0] = v0*wv[1] + b0*wv[5] + b1*wv[6] + b2*wv[7];
    av[1] = v1*wv[2] - b0*wv[5] + b3*wv[8] + b4*wv[9];
    av[2] = v2*wv[3] - b1*wv[6] - b3*wv[8] + b5*wv[10];
    av[3] = v3*wv[4] - b2*wv[7] - b4*wv[9] - b5*wv[10];

    float cq = s0*wq[0] + u0*wq[1] + u1*wq[2] + u2*wq[3] + u3*wq[4];
    float ck = s0*wk[0] + u0*wk[1] + u1*wk[2] + u2*wk[3] + u3*wk[4];
    float cv = s0*wv[0] + u0*wv[1] + u1*wv[2] + u2*wv[3] + u3*wv[4];

#pragma unroll
    for (int d = 0; d < 4; ++d) {
        P[WS_AQ + d * HID + h] = aq[d];
        P[WS_AK + d * HID + h] = ak[d];
    }
    P[WS_CQ + h] = cq;
    P[WS_CK + h] = ck;

    // reduce a_vw[d] = sum_h av[d]*wh[h];  c_vw = sum_h cv*wh[h]
    const float w = wh[h];
    float r[5] = { av[0]*w, av[1]*w, av[2]*w, av[3]*w, cv*w };
#pragma unroll
    for (int off = 16; off > 0; off >>= 1) {
#pragma unroll
        for (int i = 0; i < 5; ++i) r[i] += __shfl_down(r[i], off, 32);
    }
    if (h == 0) {
        P[WS_AVW + 0] = r[0]; P[WS_AVW + 1] = r[1];
        P[WS_AVW + 2] = r[2]; P[WS_AVW + 3] = r[3];
        P[WS_CVW]     = r[4];
    }
}

__device__ __forceinline__ float phi1(float z) {
    return (z >= 0.0f ? z : 0.01f * z) + 1.0f;
}

__global__ __launch_bounds__(TB) void ga_main(
    const float* __restrict__ x,       // (B, L, 4)
    const float* __restrict__ P,       // ws params
    const float* __restrict__ b_head,
    float* __restrict__ out,           // pred (B*T) then weights (B*T*8)
    int B, int L)
{
    const int T   = L - LOOKBACK;
    const int bb  = blockIdx.y;
    const int t0  = blockIdx.x * TB;
    const int tid = threadIdx.x;

    __shared__ float sK[NPOS * KST];
    __shared__ float sVW[NPOS];

    const float avw0 = P[WS_AVW + 0], avw1 = P[WS_AVW + 1];
    const float avw2 = P[WS_AVW + 2], avw3 = P[WS_AVW + 3];
    const float cvw  = P[WS_CVW];

    // ---- Phase A: K rows (phi) + V.w_head for positions [t0, t0+npos) ----
    const int npos = min(NPOS, L - t0);
    for (int pos = tid; pos < npos; pos += TB) {
        const float4 xv = *reinterpret_cast<const float4*>(
            x + ((size_t)bb * L + (t0 + pos)) * 4);

        sVW[pos] = cvw + xv.x*avw0 + xv.y*avw1 + xv.z*avw2 + xv.w*avw3;

#pragma unroll
        for (int g = 0; g < 8; ++g) {
            float4 a;
            a.x = P[WS_CK + g*4 + 0]; a.y = P[WS_CK + g*4 + 1];
            a.z = P[WS_CK + g*4 + 2]; a.w = P[WS_CK + g*4 + 3];
            a.x += xv.x * P[WS_AK + 0*HID + g*4 + 0];
            a.y += xv.x * P[WS_AK + 0*HID + g*4 + 1];
            a.z += xv.x * P[WS_AK + 0*HID + g*4 + 2];
            a.w += xv.x * P[WS_AK + 0*HID + g*4 + 3];
            a.x += xv.y * P[WS_AK + 1*HID + g*4 + 0];
            a.y += xv.y * P[WS_AK + 1*HID + g*4 + 1];
            a.z += xv.y * P[WS_AK + 1*HID + g*4 + 2];
            a.w += xv.y * P[WS_AK + 1*HID + g*4 + 3];
            a.x += xv.z * P[WS_AK + 2*HID + g*4 + 0];
            a.y += xv.z * P[WS_AK + 2*HID + g*4 + 1];
            a.z += xv.z * P[WS_AK + 2*HID + g*4 + 2];
            a.w += xv.z * P[WS_AK + 2*HID + g*4 + 3];
            a.x += xv.w * P[WS_AK + 3*HID + g*4 + 0];
            a.y += xv.w * P[WS_AK + 3*HID + g*4 + 1];
            a.z += xv.w * P[WS_AK + 3*HID + g*4 + 2];
            a.w += xv.w * P[WS_AK + 3*HID + g*4 + 3];
            a.x = phi1(a.x); a.y = phi1(a.y); a.z = phi1(a.z); a.w = phi1(a.w);
            *reinterpret_cast<float4*>(&sK[pos * KST + g * 4]) = a;
        }
    }
    __syncthreads();

    // ---- Phase B: per-thread q, 8 window dots, outputs ----
    const int t = t0 + tid;
    if (t >= T) return;

    const float4 xq = *reinterpret_cast<const float4*>(
        x + ((size_t)bb * L + (t + LOOKBACK)) * 4);

    float q[HID];
#pragma unroll
    for (int g = 0; g < 8; ++g) {
#pragma unroll
        for (int c = 0; c < 4; ++c) {
            float z = P[WS_CQ + g*4 + c];
            z += xq.x * P[WS_AQ + 0*HID + g*4 + c];
            z += xq.y * P[WS_AQ + 1*HID + g*4 + c];
            z += xq.z * P[WS_AQ + 2*HID + g*4 + c];
            z += xq.w * P[WS_AQ + 3*HID + g*4 + c];
            q[g*4 + c] = phi1(z);
        }
    }

    float sc[LOOKBACK];
#pragma unroll
    for (int l = 0; l < LOOKBACK; ++l) sc[l] = 0.0f;

#pragma unroll
    for (int g = 0; g < 8; ++g) {
        const float qx = q[g*4+0], qy = q[g*4+1], qz = q[g*4+2], qw = q[g*4+3];
#pragma unroll
        for (int l = 0; l < LOOKBACK; ++l) {
            const float4 kg = *reinterpret_cast<const float4*>(
                &sK[(tid + l) * KST + g * 4]);
            sc[l] += qx*kg.x + qy*kg.y + qz*kg.z + qw*kg.w;
        }
    }

    float ssum = 0.0f, p = 0.0f;
#pragma unroll
    for (int l = 0; l < LOOKBACK; ++l) {
        ssum += sc[l];
        p    += sc[l] * sVW[tid + l];
    }
    const float inv = 1.0f / (ssum + EPS);

    out[(size_t)bb * T + t] = p * inv + b_head[0];

    float* wout = out + (size_t)B * T + ((size_t)bb * T + t) * LOOKBACK;
    float4 w0 = make_float4(sc[0]*inv, sc[1]*inv, sc[2]*inv, sc[3]*inv);
    float4 w1 = make_float4(sc[4]*inv, sc[5]*inv, sc[6]*inv, sc[7]*inv);
    *reinterpret_cast<float4*>(wout)     = w0;
    *reinterpret_cast<float4*>(wout + 4) = w1;
}

extern "C" void kernel_launch(void* const* d_in, const int* in_sizes, int n_in,
                              void* d_out, int out_size, void* d_ws, size_t ws_size,
                              hipStream_t stream) {
    const float* x  = (const float*)d_in[0];
    const float* sb = (const float*)d_in[1];
    const float* vs = (const float*)d_in[2];
    const float* vb = (const float*)d_in[3];
    const float* bw = (const float*)d_in[4];
    const float* WQ = (const float*)d_in[5];
    const float* WK = (const float*)d_in[6];
    const float* WV = (const float*)d_in[7];
    const float* wh = (const float*)d_in[8];
    const float* bh = (const float*)d_in[9];
    float* out = (float*)d_out;
    float* P   = (float*)d_ws;

    // in_sizes[0] = B*L*4 ; out_size = B*(L-LOOKBACK)*(1+LOOKBACK)
    const long long bl = (long long)in_sizes[0] / 4;            // B*L
    const long long bt = (long long)out_size / (1 + LOOKBACK);  // B*(L-8)
    const int B = (int)((bl - bt) / LOOKBACK);
    const int L = (int)(bl / B);
    const int T = L - LOOKBACK;

    prep_kernel<<<1, 64, 0, stream>>>(sb, vs, vb, bw, WQ, WK, WV, wh, P);

    dim3 grid((T + TB - 1) / TB, B);
    ga_main<<<grid, TB, 0, stream>>>(x, P, bh, out, B, L);
}